// Round 4
// baseline (370.980 us; speedup 1.0000x reference)
//
#include <hip/hip_runtime.h>
#include <hip/hip_bf16.h>
#include <stdint.h>

// Problem constants
#define B_N   2048
#define XW    128      // x row width (real 64 | meta 64)
#define KDIM  512      // W_out column count (= H)
#define NROWS_W   66112
#define NROWS_PAD 66560   // padded bf16-W rows

typedef __bf16 v8bf  __attribute__((ext_vector_type(8)));
typedef float  f32x4 __attribute__((ext_vector_type(4)));

__device__ __forceinline__ unsigned short f2bf(float f) {
    uint32_t u = __float_as_uint(f);
    u += 0x7FFF + ((u >> 16) & 1);          // round-to-nearest-even
    return (unsigned short)(u >> 16);
}
__device__ __forceinline__ float elu1(float v) {
    return v > 0.0f ? v : expm1f(v);
}
__device__ __forceinline__ void gload_lds16(const void* g, void* l) {
    __builtin_amdgcn_global_load_lds(
        (const __attribute__((address_space(1))) unsigned int*)g,
        (__attribute__((address_space(3))) unsigned int*)l, 16, 0, 0);
}

// ---------------- K1: h = elu(meta @ W_in^T + b_in), stored bf16 ----------------
__global__ void k_h(const float* __restrict__ x, const float* __restrict__ W_in,
                    const float* __restrict__ b_in, unsigned short* __restrict__ hb) {
    int idx = blockIdx.x * 256 + threadIdx.x;      // b*512 + j
    int b = idx >> 9, j = idx & 511;
    const float4* xm = (const float4*)(x + (size_t)b * XW + 64);
    const float4* wr = (const float4*)(W_in + (size_t)j * 64);
    float acc = 0.f;
#pragma unroll
    for (int q = 0; q < 16; ++q) {
        float4 a = xm[q], w = wr[q];
        acc += a.x * w.x + a.y * w.y + a.z * w.z + a.w * w.w;
    }
    acc = elu1(acc + b_in[j]);
    hb[idx] = f2bf(acc);
}

// ---------------- K-conv: W_out f32 -> bf16 (padded rows zeroed) ---------------
__global__ void k_conv(const float* __restrict__ Wf, unsigned short* __restrict__ Wb) {
    size_t c = (size_t)blockIdx.x * 256 + threadIdx.x;  // 8-elem chunk id
    size_t row = c >> 6; int kk = (int)(c & 63);
    union { uint4 v; unsigned short u[8]; } o;
    o.v = (uint4){0, 0, 0, 0};
    if (row < NROWS_W) {
        const float* wp = Wf + row * KDIM + kk * 8;
        float4 w0 = *(const float4*)wp, w1 = *(const float4*)(wp + 4);
        o.u[0] = f2bf(w0.x); o.u[1] = f2bf(w0.y); o.u[2] = f2bf(w0.z); o.u[3] = f2bf(w0.w);
        o.u[4] = f2bf(w1.x); o.u[5] = f2bf(w1.y); o.u[6] = f2bf(w1.z); o.u[7] = f2bf(w1.w);
    }
    *(uint4*)(Wb + c * 8) = o.v;
}

// ---------------- K-init-ypre: ypre = b_out[32768+hh] + sum_i real_i*b_out[i*512+hh]
__global__ void k_init_ypre(const float* __restrict__ x, const float* __restrict__ b_out,
                            float* __restrict__ ypre) {
    int idx = blockIdx.x * 256 + threadIdx.x;   // b*512 + hh
    int b = idx >> 9, hh = idx & 511;
    float acc = b_out[32768 + hh];
    const float* xr = x + (size_t)b * XW;       // real part
#pragma unroll 8
    for (int i = 0; i < 64; ++i)
        acc += xr[i] * b_out[i * 512 + hh];
    ypre[idx] = acc;
}

// ---------------- K-init-out: out = b_out[66048+o] + sum_hh elu(ypre)*b_out[33280+hh*64+o]
__global__ void k_init_out(const float* __restrict__ ypre, const float* __restrict__ b_out,
                           float* __restrict__ out) {
    int idx = blockIdx.x * 256 + threadIdx.x;   // b*64 + o
    int b = idx >> 6, o = idx & 63;
    float acc = b_out[66048 + o];
    const float* yr = ypre + (size_t)b * 512;
#pragma unroll 4
    for (int hh = 0; hh < 512; ++hh)
        acc += elu1(yr[hh]) * b_out[33280 + hh * 64 + o];
    out[idx] = acc;
}

// ---------------- panel GEMM: A-in-registers, XCD-pinned, counted-vmcnt --------
// P[b,c] = sum_k h[b,k] * W[panelrow(p)+c, k]   (bf16 MFMA, K-quarters of 128)
// outAcc[b, outcol] += s(b, grp) * P            (f32 epilogue per (p,kq))
// Block: 256 rows x 128 panel-cols, 512 thr (8 waves 4x2, wave-tile 64x64).
// A (=h) fragments live in registers (16 x v8bf per kq), loaded from global (L2).
// B double-buffered in LDS via global_load_lds, pre-swizzled source.
template<int MODE>
__global__ __launch_bounds__(512, 2)
void k_pgemm(const unsigned short* __restrict__ hb,
             const unsigned short* __restrict__ Wb,
             const float* __restrict__ scaleSrc,
             float* __restrict__ outAcc) {
    constexpr int NP   = MODE ? 129 : 130;
    constexpr int OUTW = MODE ? 64 : 512;
    constexpr int SCW  = MODE ? 18 : 9;

    __shared__ char smem[32768 + SCW * 256 * 4];
    char* Bs = smem;                      // 2 x [128][128B], slot ^= row&7
    float* sc = (float*)(smem + 32768);   // [SCW][256]

    // XCD-pinned remap: blocks of one panel-split share an XCD's L2.
    const int lid = blockIdx.x;                       // [0,256)
    const int s   = (lid & 7) * 2 + (lid >> 7);       // split 0..15 -> XCD lid&7
    const int inner = (lid >> 3) & 15;
    const int m0  = (inner & 7) * 256;
    const int nh  = inner >> 3;

    const int pBeg = (NP * s) >> 4;
    const int pEnd = (NP * (s + 1)) >> 4;
    const int halfS = (MODE == 0 && pBeg >= 65) ? 1 : 0;   // uniform per split
    const int iBeg  = pBeg - halfS * 65;

    const int tid = threadIdx.x;
    const int wid = tid >> 6, l = tid & 63;
    const int lr = l & 15, lg = l >> 4;
    const int wm = wid >> 1, wn = wid & 1;                 // wave grid 4x2

    // ---- stage scales into LDS (elu applied for MODE1) ----
    for (int c = tid; c < SCW * 256; c += 512) {
        int jj = c >> 8, row = c & 255;
        float v = 1.0f;
        if (MODE == 0) {
            int i = iBeg + jj;
            if (i < 64) v = scaleSrc[(size_t)(m0 + row) * XW + i];
        } else {
            int g = (pBeg + (jj >> 1)) * 4 + nh * 2 + (jj & 1);
            if (g < 512) v = elu1(scaleSrc[(size_t)(m0 + row) * KDIM + g]);
        }
        sc[c] = v;
    }

    // ---- per-thread B fragment bases ----
    int bB[4], bX[4];
#pragma unroll
    for (int q = 0; q < 4; ++q) {
        int rb = wn * 64 + q * 16 + lr;
        bB[q] = rb * 128; bX[q] = rb & 7;
    }

    f32x4 accP[4][4], accO[4][4];
#pragma unroll
    for (int mi = 0; mi < 4; ++mi)
#pragma unroll
        for (int ni = 0; ni < 4; ++ni) {
            accP[mi][ni] = (f32x4){0.f, 0.f, 0.f, 0.f};
            accO[mi][ni] = (f32x4){0.f, 0.f, 0.f, 0.f};
        }

    for (int kq = 0; kq < 4; ++kq) {
        // ---- B chunk stage: 128 rows x 64k, pre-swizzled source, linear dst ----
        auto stageB = [&](int buf, int p, int k0c) {
            int wrow = MODE ? (33280 + p * 256 + nh * 128)
                            : ((p - halfS * 65) * 512 + halfS * 256 + nh * 128);
            const int rsub = tid >> 3;                    // 0..63
            const int sl = (tid & 7) ^ (rsub & 7);        // inverse of read-swizzle
            const unsigned short* src0 = Wb + (size_t)(wrow + rsub) * KDIM
                                       + kq * 128 + k0c * 64 + sl * 8;
            char* dst0 = Bs + buf * 16384 + tid * 16;     // wave-uniform + lane*16
#pragma unroll
            for (int q = 0; q < 2; ++q)
                gload_lds16(src0 + (size_t)q * 64 * KDIM, dst0 + q * 8192);
        };

        stageB(0, pBeg, 0);

        // ---- A fragments for this kq -> registers (direct from global, L2-hot) ----
        const unsigned short* abase = hb + (size_t)(m0 + wm * 64 + lr) * KDIM
                                    + kq * 128 + lg * 8;
        v8bf areg[4][4];                                  // [mi][k0*2+ks]
#pragma unroll
        for (int mi = 0; mi < 4; ++mi)
#pragma unroll
            for (int kk2 = 0; kk2 < 4; ++kk2)
                areg[mi][kk2] = *(const v8bf*)(abase + mi * 16 * KDIM + kk2 * 32);

        int cur = 0;
        for (int p = pBeg; p < pEnd; ++p) {
#pragma unroll
            for (int k0 = 0; k0 < 2; ++k0) {
                const bool last = (p == pEnd - 1) && (k0 == 1);
                if (!last) {
                    stageB(cur ^ 1, k0 ? p + 1 : p, k0 ^ 1);   // keep 2 in flight
                    asm volatile("s_waitcnt vmcnt(2)" ::: "memory");
                } else {
                    asm volatile("s_waitcnt vmcnt(0)" ::: "memory");
                }
                __builtin_amdgcn_s_barrier();
                asm volatile("" ::: "memory");
                char* Bbuf = Bs + cur * 16384;
                __builtin_amdgcn_s_setprio(1);
#pragma unroll
                for (int ks = 0; ks < 2; ++ks) {
                    v8bf bfr[4];
                    const int sB = ks * 4 + lg;
#pragma unroll
                    for (int ni = 0; ni < 4; ++ni)
                        bfr[ni] = *(const v8bf*)(Bbuf + bB[ni] + ((sB ^ bX[ni]) << 4));
#pragma unroll
                    for (int mi = 0; mi < 4; ++mi)
#pragma unroll
                        for (int ni = 0; ni < 4; ++ni)
                            accP[mi][ni] = __builtin_amdgcn_mfma_f32_16x16x32_bf16(
                                areg[mi][k0 * 2 + ks], bfr[ni], accP[mi][ni], 0, 0, 0);
                }
                __builtin_amdgcn_s_setprio(0);
                if (k0 == 1) {
                    // scale-accumulate P into O (vector f32, broadcast sc reads)
                    int jj = MODE ? ((p - pBeg) * 2 + wn) : (p - pBeg);
                    const f32x4* scv = (const f32x4*)(sc + jj * 256);
#pragma unroll
                    for (int mi = 0; mi < 4; ++mi) {
                        f32x4 sv = scv[wm * 16 + mi * 4 + lg];
#pragma unroll
                        for (int ni = 0; ni < 4; ++ni) {
                            accO[mi][ni] += sv * accP[mi][ni];
                            accP[mi][ni] = (f32x4){0.f, 0.f, 0.f, 0.f};
                        }
                    }
                }
                asm volatile("" ::: "memory");
                __builtin_amdgcn_s_barrier();
                cur ^= 1;
            }
        }
    }
    // ---- epilogue: atomic accumulate ----
#pragma unroll
    for (int mi = 0; mi < 4; ++mi)
#pragma unroll
        for (int ni = 0; ni < 4; ++ni)
#pragma unroll
            for (int r = 0; r < 4; ++r) {
                int row = wm * 64 + mi * 16 + lg * 4 + r;
                int col = MODE ? (ni * 16 + lr)
                               : (halfS * 256 + nh * 128 + wn * 64 + ni * 16 + lr);
                atomicAdd(outAcc + (size_t)(m0 + row) * OUTW + col, accO[mi][ni][r]);
            }
}

extern "C" void kernel_launch(void* const* d_in, const int* in_sizes, int n_in,
                              void* d_out, int out_size, void* d_ws, size_t ws_size,
                              hipStream_t stream) {
    const float* x     = (const float*)d_in[0];
    const float* W_in  = (const float*)d_in[1];
    const float* b_in  = (const float*)d_in[2];
    const float* W_out = (const float*)d_in[3];
    const float* b_out = (const float*)d_in[4];
    float* out = (float*)d_out;

    char* ws = (char*)d_ws;
    unsigned short* hb = (unsigned short*)ws;            // 2 MB  h bf16
    float* ypre        = (float*)(ws + (2u << 20));      // 4 MB
    unsigned short* Wb = (unsigned short*)(ws + (6u << 20));   // 68.2 MB bf16 W_out

    k_h<<<(B_N * 512) / 256, 256, 0, stream>>>(x, W_in, b_in, hb);
    k_conv<<<(NROWS_PAD * KDIM / 8) / 256, 256, 0, stream>>>(W_out, Wb);

    // ypre := bias terms (replaces memset + separate finalize)
    k_init_ypre<<<(B_N * 512) / 256, 256, 0, stream>>>(x, b_out, ypre);

    // Stage 2: ypre += sum_i real_i * (h @ W_i^T)  (+ l_in_b panel, scale 1)
    k_pgemm<0><<<256, 512, 0, stream>>>(hb, Wb, x, ypre);

    // out := bias terms + sum_hh elu(ypre)*l_out_w-bias-part (replaces memset+fin)
    k_init_out<<<(B_N * 64) / 256, 256, 0, stream>>>(ypre, b_out, out);

    // Stage 3: out += sum_h' elu(ypre_h') * (h @ W2_h'^T)  (+ l_out_b panel)
    k_pgemm<1><<<256, 512, 0, stream>>>(hb, Wb, ypre, out);
}